// Round 2
// baseline (10.370 us; speedup 1.0000x reference)
//
#include <hip/hip_runtime.h>

// out(x) per branch k:  sum_h w_k2[h] * relu(w_k1[h]*x + b_k1[h]) + b_k2
// With b_k1 == 0 (true for harness inputs) each branch is piecewise-linear
// around 0:  out = x * (x>0 ? s_pos : s_neg) + b_k2, where
// s_pos = sum_{w1[h]>0} w1[h]*w2[h], s_neg = sum_{w1[h]<0} w1[h]*w2[h].
// Each WAVE redundantly computes the 4 slopes via a barrier-free __shfl_xor
// butterfly (weights are L1/L2-broadcast, ~2 KB); a general 128-iter fallback
// path is kept behind a uniform __any(b1 != 0) flag.

__global__ __launch_bounds__(256) void PredEnvHatYSep_kernel(
    const int*   __restrict__ g,
    const float* __restrict__ x,
    const float* __restrict__ w11, const float* __restrict__ b11,
    const float* __restrict__ w12, const float* __restrict__ b12,
    const float* __restrict__ w21, const float* __restrict__ b21,
    const float* __restrict__ w22, const float* __restrict__ b22,
    float* __restrict__ out, int n)
{
    const int tid  = threadIdx.x;
    const int lane = tid & 63;

    // ---- Issue main element loads FIRST (hide HBM latency under the
    //      slope reduction). 8 elements/thread = 2 x (int4 + float4). ----
    const int ng = n >> 2;                      // complete float4 groups
    const int i0 = blockIdx.x * 512 + tid;
    const int i1 = i0 + 256;
    const bool v0 = i0 < ng;
    const bool v1 = i1 < ng;

    int4   g0 = {0,0,0,0}, g1 = {0,0,0,0};
    float4 x0 = {0,0,0,0}, x1 = {0,0,0,0};
    if (v0) { g0 = reinterpret_cast<const int4*>(g)[i0];
              x0 = reinterpret_cast<const float4*>(x)[i0]; }
    if (v1) { g1 = reinterpret_cast<const int4*>(g)[i1];
              x1 = reinterpret_cast<const float4*>(x)[i1]; }

    // ---- Wave-local slope reduction (no LDS, no __syncthreads).
    //      Each lane covers h = lane and h = lane + 64 (H == 128). ----
    const float a0 = w11[lane], a1 = w11[lane + 64];
    const float c0 = w21[lane], c1w = w21[lane + 64];
    const float p0 = a0 * w12[lane], p1 = a1 * w12[lane + 64];
    const float q0 = c0 * w22[lane], q1 = c1w * w22[lane + 64];

    float pos1 = (a0 > 0.f ? p0 : 0.f) + (a1 > 0.f ? p1 : 0.f);
    float neg1 = (a0 < 0.f ? p0 : 0.f) + (a1 < 0.f ? p1 : 0.f);
    float pos2 = (c0 > 0.f ? q0 : 0.f) + (c1w > 0.f ? q1 : 0.f);
    float neg2 = (c0 < 0.f ? q0 : 0.f) + (c1w < 0.f ? q1 : 0.f);

    const bool badl = (b11[lane] != 0.f) | (b11[lane + 64] != 0.f) |
                      (b21[lane] != 0.f) | (b21[lane + 64] != 0.f);

    #pragma unroll
    for (int off = 1; off < 64; off <<= 1) {
        pos1 += __shfl_xor(pos1, off);
        neg1 += __shfl_xor(neg1, off);
        pos2 += __shfl_xor(pos2, off);
        neg2 += __shfl_xor(neg2, off);
    }
    const bool bad = __any(badl);
    const float cc1 = b12[0];
    const float cc2 = b22[0];

    // ---- Elementwise math ----
    auto fastf = [&](int gi, float xi) -> float {
        const bool  br1 = (gi == 0);
        const float sp  = br1 ? pos1 : pos2;
        const float sn  = br1 ? neg1 : neg2;
        const float cc  = br1 ? cc1  : cc2;
        const float o   = xi * (xi > 0.f ? sp : sn) + cc;
        return ((unsigned)gi <= 1u) ? o : 0.f;
    };
    auto slowf = [&](int gi, float xi) -> float {
        float acc1 = 0.f, acc2 = 0.f;
        for (int h = 0; h < 128; ++h) {
            acc1 += w12[h] * fmaxf(xi * w11[h] + b11[h], 0.f);
            acc2 += w22[h] * fmaxf(xi * w21[h] + b21[h], 0.f);
        }
        return gi == 0 ? acc1 + cc1 : (gi == 1 ? acc2 + cc2 : 0.f);
    };

    float4 o0, o1;
    if (!bad) {
        o0.x = fastf(g0.x, x0.x); o0.y = fastf(g0.y, x0.y);
        o0.z = fastf(g0.z, x0.z); o0.w = fastf(g0.w, x0.w);
        o1.x = fastf(g1.x, x1.x); o1.y = fastf(g1.y, x1.y);
        o1.z = fastf(g1.z, x1.z); o1.w = fastf(g1.w, x1.w);
    } else {
        o0.x = slowf(g0.x, x0.x); o0.y = slowf(g0.y, x0.y);
        o0.z = slowf(g0.z, x0.z); o0.w = slowf(g0.w, x0.w);
        o1.x = slowf(g1.x, x1.x); o1.y = slowf(g1.y, x1.y);
        o1.z = slowf(g1.z, x1.z); o1.w = slowf(g1.w, x1.w);
    }
    if (v0) reinterpret_cast<float4*>(out)[i0] = o0;
    if (v1) reinterpret_cast<float4*>(out)[i1] = o1;

    // ---- Scalar tail (n % 4 != 0; never taken for N = 2^21) ----
    if (blockIdx.x == 0) {
        const int t = n & 3, base = n & ~3;
        if (tid < t) {
            const int   gi = g[base + tid];
            const float xi = x[base + tid];
            out[base + tid] = bad ? slowf(gi, xi) : fastf(gi, xi);
        }
    }
}

extern "C" void kernel_launch(void* const* d_in, const int* in_sizes, int n_in,
                              void* d_out, int out_size, void* d_ws, size_t ws_size,
                              hipStream_t stream) {
    const int*   g   = (const int*)  d_in[0];
    const float* x   = (const float*)d_in[1];
    const float* w11 = (const float*)d_in[2];
    const float* b11 = (const float*)d_in[3];
    const float* w12 = (const float*)d_in[4];
    const float* b12 = (const float*)d_in[5];
    const float* w21 = (const float*)d_in[6];
    const float* b21 = (const float*)d_in[7];
    const float* w22 = (const float*)d_in[8];
    const float* b22 = (const float*)d_in[9];
    float* out = (float*)d_out;

    const int n  = in_sizes[1];                    // N elements
    const int ng = n >> 2;                         // float4 groups
    int blocks = (ng + 511) / 512;                 // 8 elems/thread, 256 thr
    if (blocks < 1) blocks = 1;

    PredEnvHatYSep_kernel<<<blocks, 256, 0, stream>>>(
        g, x, w11, b11, w12, b12, w21, b21, w22, b22, out, n);
}

// Round 3
// 10.155 us; speedup vs baseline: 1.0211x; 1.0211x over previous
//
#include <hip/hip_runtime.h>

// out(x) per branch k:  sum_h w_k2[h] * relu(w_k1[h]*x + b_k1[h]) + b_k2
// With b_k1 == 0 (true for harness inputs) each branch is piecewise-linear
// around 0:  out = x * (x>0 ? s_pos : s_neg) + b_k2.
// Slopes are reduced per-wave via __shfl_xor butterfly, entirely under the
// shadow of the main element loads. General 128-iter fallback kept behind a
// uniform __any(b1 != 0) flag.
// This round: 16 elems/thread, all 8 vector loads issued before any compute
// (max MLP), 512 blocks. Testing whether device time or launch overhead
// dominates the ~10 us plateau.

#define GROUPS 4   // float4 groups per thread (16 elements)

__global__ __launch_bounds__(256) void PredEnvHatYSep_kernel(
    const int*   __restrict__ g,
    const float* __restrict__ x,
    const float* __restrict__ w11, const float* __restrict__ b11,
    const float* __restrict__ w12, const float* __restrict__ b12,
    const float* __restrict__ w21, const float* __restrict__ b21,
    const float* __restrict__ w22, const float* __restrict__ b22,
    float* __restrict__ out, int n)
{
    const int tid  = threadIdx.x;
    const int lane = tid & 63;

    // ---- Issue ALL element loads first (8 x 16B in flight) ----
    const int ng   = n >> 2;                    // complete float4 groups
    const int base = blockIdx.x * (256 * GROUPS) + tid;

    int4   gv[GROUPS];
    float4 xv[GROUPS];
    bool   valid[GROUPS];
    #pragma unroll
    for (int k = 0; k < GROUPS; ++k) {
        const int i = base + k * 256;
        valid[k] = i < ng;
        if (valid[k]) {
            gv[k] = reinterpret_cast<const int4*>(g)[i];
            xv[k] = reinterpret_cast<const float4*>(x)[i];
        } else {
            gv[k] = make_int4(0, 0, 0, 0);
            xv[k] = make_float4(0.f, 0.f, 0.f, 0.f);
        }
    }

    // ---- Wave-local slope reduction (under load shadow) ----
    const float a0 = w11[lane], a1 = w11[lane + 64];
    const float c0 = w21[lane], c1w = w21[lane + 64];
    const float p0 = a0 * w12[lane], p1 = a1 * w12[lane + 64];
    const float q0 = c0 * w22[lane], q1 = c1w * w22[lane + 64];

    float pos1 = (a0 > 0.f ? p0 : 0.f) + (a1 > 0.f ? p1 : 0.f);
    float neg1 = (a0 < 0.f ? p0 : 0.f) + (a1 < 0.f ? p1 : 0.f);
    float pos2 = (c0 > 0.f ? q0 : 0.f) + (c1w > 0.f ? q1 : 0.f);
    float neg2 = (c0 < 0.f ? q0 : 0.f) + (c1w < 0.f ? q1 : 0.f);

    const bool badl = (b11[lane] != 0.f) | (b11[lane + 64] != 0.f) |
                      (b21[lane] != 0.f) | (b21[lane + 64] != 0.f);

    #pragma unroll
    for (int off = 1; off < 64; off <<= 1) {
        pos1 += __shfl_xor(pos1, off);
        neg1 += __shfl_xor(neg1, off);
        pos2 += __shfl_xor(pos2, off);
        neg2 += __shfl_xor(neg2, off);
    }
    const bool  bad = __any(badl);
    const float cc1 = b12[0];
    const float cc2 = b22[0];

    auto fastf = [&](int gi, float xi) -> float {
        const bool  br1 = (gi == 0);
        const float sp  = br1 ? pos1 : pos2;
        const float sn  = br1 ? neg1 : neg2;
        const float cc  = br1 ? cc1  : cc2;
        const float o   = xi * (xi > 0.f ? sp : sn) + cc;
        return ((unsigned)gi <= 1u) ? o : 0.f;
    };
    auto slowf = [&](int gi, float xi) -> float {
        float acc1 = 0.f, acc2 = 0.f;
        for (int h = 0; h < 128; ++h) {
            acc1 += w12[h] * fmaxf(xi * w11[h] + b11[h], 0.f);
            acc2 += w22[h] * fmaxf(xi * w21[h] + b21[h], 0.f);
        }
        return gi == 0 ? acc1 + cc1 : (gi == 1 ? acc2 + cc2 : 0.f);
    };

    if (!bad) {
        #pragma unroll
        for (int k = 0; k < GROUPS; ++k) {
            if (!valid[k]) continue;
            float4 ov;
            ov.x = fastf(gv[k].x, xv[k].x);
            ov.y = fastf(gv[k].y, xv[k].y);
            ov.z = fastf(gv[k].z, xv[k].z);
            ov.w = fastf(gv[k].w, xv[k].w);
            reinterpret_cast<float4*>(out)[base + k * 256] = ov;
        }
    } else {
        #pragma unroll
        for (int k = 0; k < GROUPS; ++k) {
            if (!valid[k]) continue;
            float4 ov;
            ov.x = slowf(gv[k].x, xv[k].x);
            ov.y = slowf(gv[k].y, xv[k].y);
            ov.z = slowf(gv[k].z, xv[k].z);
            ov.w = slowf(gv[k].w, xv[k].w);
            reinterpret_cast<float4*>(out)[base + k * 256] = ov;
        }
    }

    // ---- Scalar tail (n % 4 != 0; never taken for N = 2^21) ----
    if (blockIdx.x == 0) {
        const int t = n & 3, tb = n & ~3;
        if (tid < t) {
            const int   gi = g[tb + tid];
            const float xi = x[tb + tid];
            out[tb + tid] = bad ? slowf(gi, xi) : fastf(gi, xi);
        }
    }
}

extern "C" void kernel_launch(void* const* d_in, const int* in_sizes, int n_in,
                              void* d_out, int out_size, void* d_ws, size_t ws_size,
                              hipStream_t stream) {
    const int*   g   = (const int*)  d_in[0];
    const float* x   = (const float*)d_in[1];
    const float* w11 = (const float*)d_in[2];
    const float* b11 = (const float*)d_in[3];
    const float* w12 = (const float*)d_in[4];
    const float* b12 = (const float*)d_in[5];
    const float* w21 = (const float*)d_in[6];
    const float* b21 = (const float*)d_in[7];
    const float* w22 = (const float*)d_in[8];
    const float* b22 = (const float*)d_in[9];
    float* out = (float*)d_out;

    const int n  = in_sizes[1];                    // N elements
    const int ng = (n + 3) >> 2;                   // float4 groups (ceil)
    int blocks = (ng + 256 * GROUPS - 1) / (256 * GROUPS);
    if (blocks < 1) blocks = 1;

    PredEnvHatYSep_kernel<<<blocks, 256, 0, stream>>>(
        g, x, w11, b11, w12, b12, w21, b21, w22, b22, out, n);
}